// Round 1
// 493.832 us; speedup vs baseline: 1.1959x; 1.1959x over previous
//
#include <hip/hip_runtime.h>

typedef unsigned short u16;
typedef unsigned int u32;

#define Bb 2
#define Lc 2048
#define Dc 2048
#define Hc 16
#define DhC 128

typedef __bf16 bf16x8 __attribute__((ext_vector_type(8)));
typedef float f32x4 __attribute__((ext_vector_type(4)));
typedef float f32x16 __attribute__((ext_vector_type(16)));

__device__ __forceinline__ u16 f2b(float f) {
  u32 u = __float_as_uint(f);
  u32 r = (u + 0x7fffu + ((u >> 16) & 1u)) >> 16;
  return (u16)r;
}
__device__ __forceinline__ float b2f(u16 u) {
  return __uint_as_float(((u32)u) << 16);
}

// pack 2 f32 -> 1 u32 of 2 bf16 (lo in low half) -- T12 recipe, no builtin
__device__ __forceinline__ u32 cvtpk(float lo, float hi) {
  u32 r;
  asm("v_cvt_pk_bf16_f32 %0, %1, %2" : "=v"(r) : "v"(lo), "v"(hi));
  return r;
}

// async global->LDS DMA, 16B/lane; LDS dest = wave-uniform base + lane*16
__device__ __forceinline__ void gll16(const void* g, void* l) {
  __builtin_amdgcn_global_load_lds(
      (const __attribute__((address_space(1))) u32*)g,
      (__attribute__((address_space(3))) u32*)l, 16, 0, 0);
}

// ---------------------------------------------------------------------------
// Dtype sniffer + x canonicalize (kept; inputs verified bf16-compatible r4).
// ---------------------------------------------------------------------------
__global__ __launch_bounds__(256) void sniff_dtype(const u16* __restrict__ x,
                                                   int* __restrict__ flag) {
  __shared__ int bad;
  if (threadIdx.x == 0) bad = 0;
  __syncthreads();
  int local = 0;
  for (int i = threadIdx.x; i < 65536; i += 256) {
    float v = fabsf(b2f(x[i]));
    if (!(v < 1000.f)) local = 1;
  }
  if (local) atomicOr(&bad, 1);
  __syncthreads();
  if (threadIdx.x == 0) *flag = bad;
}

__global__ __launch_bounds__(256) void conv_x(const void* __restrict__ in,
                                              u16* __restrict__ out,
                                              const int* __restrict__ flag) {
  const int f32 = *flag;
  const int i0 = (blockIdx.x * 256 + threadIdx.x) * 4;
  if (f32) {
    const float* p = (const float*)in;
#pragma unroll
    for (int j = 0; j < 4; j++) out[i0 + j] = f2b(p[i0 + j]);
  } else {
    const u16* p = (const u16*)in;
#pragma unroll
    for (int j = 0; j < 4; j++) out[i0 + j] = p[i0 + j];
  }
}

// ---------------------------------------------------------------------------
// 2048x2048 transpose with dtype conversion (weights -> bf16 W^T).
// ---------------------------------------------------------------------------
__global__ __launch_bounds__(256) void transpose2d_conv(const void* __restrict__ in,
                                                        u16* __restrict__ out,
                                                        const int* __restrict__ flag) {
  __shared__ __align__(16) u16 tile[64][65];
  const int f32 = *flag;
  const int r0 = blockIdx.y * 64, c0 = blockIdx.x * 64;
  const int tc = threadIdx.x & 63, tr4 = threadIdx.x >> 6;
#pragma unroll
  for (int p = 0; p < 16; p++) {
    int r = tr4 + p * 4;
    size_t idx = (size_t)(r0 + r) * 2048 + c0 + tc;
    tile[r][tc] = f32 ? f2b(((const float*)in)[idx]) : ((const u16*)in)[idx];
  }
  __syncthreads();
#pragma unroll
  for (int p = 0; p < 16; p++) {
    int rr = tr4 + p * 4;
    out[(size_t)(c0 + rr) * 2048 + r0 + tc] = tile[tc][rr];
  }
}

// ---------------------------------------------------------------------------
// GEMM: C[4096,2048] = A @ Bt^T. m97 structure + XOR-swizzled LDS:
// row r (64 elems = 8 chunks of 16B): logical chunk c stored at slot c^(r&7).
// Read banks: bijective per 8-row group -> 2 lanes/bank (free, m136).
// ---------------------------------------------------------------------------
template <typename OutT>
__device__ __forceinline__ void gemm_bt_core(const u16* __restrict__ A,
                                             const u16* __restrict__ Bt,
                                             OutT* __restrict__ C) {
  constexpr int K = 2048, N = 2048;
  __shared__ __align__(16) u16 As[128 * 64];
  __shared__ __align__(16) u16 Bs[128 * 64];
  const int tid = threadIdx.x;
  const int lane = tid & 63, wid = tid >> 6;
  const int wm = (wid >> 1) * 64, wn = (wid & 1) * 64;
  const int m0 = blockIdx.x * 128, n0 = blockIdx.y * 128;
  const int quad = lane >> 4, l15 = lane & 15;
  const int sw = l15 & 7;  // read-side swizzle key

  const f32x4 fz = {0.f, 0.f, 0.f, 0.f};
  f32x4 acc[4][4];
#pragma unroll
  for (int i = 0; i < 4; i++)
#pragma unroll
    for (int j = 0; j < 4; j++) acc[i][j] = fz;

  // staging map (per wave, per pass p): rows p*32+wid*8+(lane>>3), slot lane&7
  const int srl = (lane >> 3);
  const int ssl = lane & 7;

  for (int k0 = 0; k0 < K; k0 += 64) {
#pragma unroll
    for (int p = 0; p < 4; p++) {
      const int r = p * 32 + wid * 8 + srl;
      const int c = ssl ^ (r & 7);
      u16* lb = As + (p * 256 + wid * 64) * 8;
      gll16(A + (size_t)(m0 + r) * K + k0 + c * 8, lb);
    }
#pragma unroll
    for (int p = 0; p < 4; p++) {
      const int r = p * 32 + wid * 8 + srl;
      const int c = ssl ^ (r & 7);
      u16* lb = Bs + (p * 256 + wid * 64) * 8;
      gll16(Bt + (size_t)(n0 + r) * K + k0 + c * 8, lb);
    }
    __syncthreads();
#pragma unroll
    for (int ks = 0; ks < 2; ks++) {
      bf16x8 af[4], bfr[4];
#pragma unroll
      for (int t = 0; t < 4; t++) {
        const int cc = ((ks * 4 + quad) ^ sw) * 8;
        af[t]  = *(const bf16x8*)(&As[(wm + t * 16 + l15) * 64 + cc]);
        bfr[t] = *(const bf16x8*)(&Bs[(wn + t * 16 + l15) * 64 + cc]);
      }
#pragma unroll
      for (int mt = 0; mt < 4; mt++)
#pragma unroll
        for (int nt = 0; nt < 4; nt++)
          acc[mt][nt] = __builtin_amdgcn_mfma_f32_16x16x32_bf16(af[mt], bfr[nt], acc[mt][nt], 0, 0, 0);
    }
    __syncthreads();
  }
#pragma unroll
  for (int mt = 0; mt < 4; mt++)
#pragma unroll
    for (int nt = 0; nt < 4; nt++) {
      int col = n0 + wn + nt * 16 + l15;
#pragma unroll
      for (int r = 0; r < 4; r++) {
        int row = m0 + wm + mt * 16 + quad * 4 + r;
        float v = acc[mt][nt][r];
        if constexpr (sizeof(OutT) == 2)
          C[(size_t)row * N + col] = f2b(v);
        else
          C[(size_t)row * N + col] = v;
      }
    }
}

__global__ __launch_bounds__(256) void gemm_bt(const u16* __restrict__ A,
                                               const u16* __restrict__ Bt,
                                               u16* __restrict__ C) {
  gemm_bt_core<u16>(A, Bt, C);
}
__global__ __launch_bounds__(256) void gemm_bt_f32(const u16* __restrict__ A,
                                                   const u16* __restrict__ Bt,
                                                   float* __restrict__ C) {
  gemm_bt_core<float>(A, Bt, C);
}

// ---------------------------------------------------------------------------
// V (B,L,H,Dh) -> Vt (B,H,Dh,L)
// ---------------------------------------------------------------------------
__global__ __launch_bounds__(256) void transpose_v_k(const u16* __restrict__ V,
                                                     u16* __restrict__ Vt) {
  __shared__ __align__(16) u16 tile[64][65];
  const int z = blockIdx.z;
  const int b = z >> 4, h = z & 15;
  const int l0 = blockIdx.y * 64, d0 = blockIdx.x * 64;
  const int tc = threadIdx.x & 63, tr4 = threadIdx.x >> 6;
#pragma unroll
  for (int p = 0; p < 16; p++) {
    int l = tr4 + p * 4;
    tile[l][tc] = V[(size_t)((b * Lc + l0 + l) * Hc + h) * DhC + d0 + tc];
  }
  __syncthreads();
#pragma unroll
  for (int p = 0; p < 16; p++) {
    int dd = tr4 + p * 4;
    Vt[((size_t)z * DhC + d0 + dd) * Lc + l0 + tc] = tile[tc][dd];
  }
}

// ---------------------------------------------------------------------------
// RoPE in place on Q and K; Q additionally scaled by 1/sqrt(Dh).
// ---------------------------------------------------------------------------
__global__ __launch_bounds__(256) void rope_qk(u16* __restrict__ Q, u16* __restrict__ K) {
  const int idx = blockIdx.x * 256 + threadIdx.x;
  const int j = idx & 63;
  const int l = (idx >> 10) & 2047;
  const float inv = expf(-0.2050369278f * (float)j);  // theta^(-j/64)
  const float ang = (float)l * inv;
  float s, c;
  sincosf(ang, &s, &c);
  const size_t off = (size_t)idx * 2;
  const float q0 = b2f(Q[off]), q1 = b2f(Q[off + 1]);
  const float k0 = b2f(K[off]), k1 = b2f(K[off + 1]);
  const float sc = 0.08838834764f;  // 1/sqrt(128)
  Q[off]     = f2b((q0 * c - q1 * s) * sc);
  Q[off + 1] = f2b((q1 * c + q0 * s) * sc);
  K[off]     = f2b(k0 * c - k1 * s);
  K[off + 1] = f2b(k1 * c + k0 * s);
}

// ---------------------------------------------------------------------------
// Flash attention (causal), r7: 32x32 swapped-operand rewrite.
//  Structure: 4 waves x 32 q-rows = 128 q-rows/block; KV tile 64; grid 16x32.
//  - swapped QK^T: S^T = mfma(K_frag, Q_frag) -> lane owns col q=l31; row max
//    and row sum become IN-LANE reductions over 32 regs + ONE shfl_xor(32)
//    (was: 2x 4-hop shfl chains per row).
//  - P -> PV A-fragment fully in-register: v_cvt_pk_bf16_f32 pairs + one
//    cross-half shfl exchange (kills Ps LDS round-trip + 16 ds_write_b16).
//  - defer-max (T13, THR=8): skip O-rescale while tile max grows < 8.
//  - s_setprio(1) around MFMA clusters (T5; +4-7% attn per m191).
//  - pair-balanced qt remap: co-resident blocks (x,y),(x,y+16) get qt summing
//    to 15 -> per-CU tile-step count ~constant 34 (was 4..64: same-qt blocks
//    stacked on one CU -> the measured 11.5% occupancy tail).
//  - DMA double-buffer K/V kept (gll16, XOR swizzle keys r&15 / r&7), one
//    barrier per KV tile (vmcnt(0)+lgkmcnt(0) at barrier drains prefetch).
// LDS: 2*16K (Ks) + 2*16K (Vs) = 64KB -> 2 blocks/CU (8 waves/CU).
// ---------------------------------------------------------------------------
#define NEGBIG (-3.0e30f)
__global__ __launch_bounds__(256, 2) void flash_attn(const u16* __restrict__ Q,
                                                     const u16* __restrict__ Kg,
                                                     const u16* __restrict__ Vt,
                                                     u16* __restrict__ O) {
  __shared__ __align__(16) u16 Ks[2][64 * 128];
  __shared__ __align__(16) u16 Vs[2][128 * 64];
  const int tid = threadIdx.x;
  const int lane = tid & 63, w = tid >> 6;
  const int l31 = lane & 31, hib = lane >> 5;
  const int bh = blockIdx.y;
  const int b = bh >> 4, h = bh & 15;
  // pair-balance: blocks (x,y) and (x,y+16) co-reside on a CU; qt sums to 15
  const int qt = (bh & 16) ? (int)blockIdx.x : (15 - (int)blockIdx.x);
  const int q0 = qt * 128;
  const int qw0 = q0 + w * 32;   // this wave's first q row
  const int nkv = 2 * qt + 2;    // causal KV tiles for this block

  // staging maps (wave-uniform LDS bases; per-lane global chunk choice)
  const int krl = lane >> 4, ksl = lane & 15;  // K: 4 rows x 16 chunks / wave
  const int vrl = lane >> 3, vsl = lane & 7;   // V: 8 rows x 8 chunks / wave

  // Q fragments (B-operand: col = q = l31, k = d = 16*s + 8*hib + j)
  bf16x8 qf[8];
  {
    const u16* qptr = Q + ((size_t)(b * Lc + qw0 + l31) * Hc + h) * DhC + 8 * hib;
#pragma unroll
    for (int s = 0; s < 8; s++) qf[s] = *(const bf16x8*)(qptr + s * 16);
  }

  // prologue: DMA tile 0 into buffer 0
  {
#pragma unroll
    for (int p = 0; p < 4; p++) {
      const int r = p * 16 + w * 4 + krl;
      const int c = ksl ^ (r & 15);
      gll16(Kg + ((size_t)(b * Lc + r) * Hc + h) * DhC + c * 8,
            &Ks[0][(p * 256 + w * 64) * 8]);
    }
#pragma unroll
    for (int p = 0; p < 4; p++) {
      const int r = p * 32 + w * 8 + vrl;
      const int c = vsl ^ (r & 7);
      gll16(Vt + ((size_t)bh * DhC + r) * Lc + c * 8,
            &Vs[0][(p * 256 + w * 64) * 8]);
    }
  }

  f32x16 o[4];
#pragma unroll
  for (int dt = 0; dt < 4; dt++) o[dt] = (f32x16)0.0f;
  float mrow = NEGBIG, lrow = 0.f;

  __syncthreads();  // tile 0 DMA complete

  for (int kvt = 0; kvt < nkv; kvt++) {
    const int cur = kvt & 1;
    const u16* Ksc = Ks[cur];
    const u16* Vsc = Vs[cur];

    // prefetch next tile into other buffer (in flight during compute)
    if (kvt + 1 < nkv) {
      const int nv0 = (kvt + 1) * 64;
      const int nxt = cur ^ 1;
#pragma unroll
      for (int p = 0; p < 4; p++) {
        const int r = p * 16 + w * 4 + krl;
        const int c = ksl ^ (r & 15);
        gll16(Kg + ((size_t)(b * Lc + nv0 + r) * Hc + h) * DhC + c * 8,
              &Ks[nxt][(p * 256 + w * 64) * 8]);
      }
#pragma unroll
      for (int p = 0; p < 4; p++) {
        const int r = p * 32 + w * 8 + vrl;
        const int c = vsl ^ (r & 7);
        gll16(Vt + ((size_t)bh * DhC + r) * Lc + nv0 + c * 8,
              &Vs[nxt][(p * 256 + w * 64) * 8]);
      }
    }

    const int kv0 = kvt * 64;
    const bool active = (kv0 <= qw0 + 31);  // wave-uniform; skip if all masked
    if (active) {
      // ---- S^T = K @ Q^T : lane holds S[kv = 32t+crow(reg,hib)][q = l31] ----
      f32x16 s0 = (f32x16)0.0f, s1 = (f32x16)0.0f;
      __builtin_amdgcn_s_setprio(1);
#pragma unroll
      for (int s = 0; s < 8; s++) {
        const int ch = ((2 * s + hib) ^ (l31 & 15)) * 8;
        bf16x8 k0 = *(const bf16x8*)(&Ksc[l31 * 128 + ch]);
        bf16x8 k1 = *(const bf16x8*)(&Ksc[(32 + l31) * 128 + ch]);
        s0 = __builtin_amdgcn_mfma_f32_32x32x16_bf16(k0, qf[s], s0, 0, 0, 0);
        s1 = __builtin_amdgcn_mfma_f32_32x32x16_bf16(k1, qf[s], s1, 0, 0, 0);
      }
      __builtin_amdgcn_s_setprio(0);

      // causal mask (only partial on the last two tiles of this wave)
      if (kv0 + 63 > qw0) {
        const int qg = qw0 + l31;
#pragma unroll
        for (int r = 0; r < 16; r++) {
          const int cr = (r & 3) + 8 * (r >> 2) + 4 * hib;
          if (kv0 + cr > qg) s0[r] = NEGBIG;
          if (kv0 + 32 + cr > qg) s1[r] = NEGBIG;
        }
      }

      // ---- online softmax: in-lane tree + one cross-half shfl ----
      float mx;
      {
        float a[8];
#pragma unroll
        for (int i = 0; i < 8; i++)
          a[i] = fmaxf(fmaxf(s0[i], s0[i + 8]), fmaxf(s1[i], s1[i + 8]));
        float b0 = fmaxf(a[0], a[4]), b1 = fmaxf(a[1], a[5]);
        float b2 = fmaxf(a[2], a[6]), b3 = fmaxf(a[3], a[7]);
        mx = fmaxf(fmaxf(b0, b1), fmaxf(b2, b3));
      }
      mx = fmaxf(mx, __shfl_xor(mx, 32, 64));

      // defer-max (T13): rescale only when the running max grows > 8
      if (!__all(mx - mrow <= 8.f)) {
        const float mnew = fmaxf(mrow, mx);
        const float al = __expf(mrow - mnew);
#pragma unroll
        for (int dt = 0; dt < 4; dt++)
#pragma unroll
          for (int e = 0; e < 16; e++) o[dt][e] *= al;
        lrow *= al;
        mrow = mnew;
      }

#pragma unroll
      for (int i = 0; i < 16; i++) {
        s0[i] = __expf(s0[i] - mrow);
        s1[i] = __expf(s1[i] - mrow);
      }
      float sm;
      {
        float a[8];
#pragma unroll
        for (int i = 0; i < 8; i++)
          a[i] = (s0[i] + s0[i + 8]) + (s1[i] + s1[i + 8]);
        sm = ((a[0] + a[4]) + (a[1] + a[5])) + ((a[2] + a[6]) + (a[3] + a[7]));
      }
      sm += __shfl_xor(sm, 32, 64);
      lrow += sm;

      // ---- P (C-layout, f32) -> PV A-fragments (bf16), in-register ----
      // block B = 2t+h8 covers kv-local [16B,16B+16); lane needs kv%16 =
      // 8*hib+j. Own low quad = kv%16 in {4hib..4hib+3}, own high quad =
      // {8+4hib..}; exchange the complementary quad with lane^32.
      bf16x8 paf[4];
#pragma unroll
      for (int t = 0; t < 2; t++) {
#pragma unroll
        for (int h8 = 0; h8 < 2; h8++) {
          const int rB = 8 * h8;
          u32 lo0, lo1, hi0, hi1;
          if (t == 0) {
            lo0 = cvtpk(s0[rB + 0], s0[rB + 1]);
            lo1 = cvtpk(s0[rB + 2], s0[rB + 3]);
            hi0 = cvtpk(s0[rB + 4], s0[rB + 5]);
            hi1 = cvtpk(s0[rB + 6], s0[rB + 7]);
          } else {
            lo0 = cvtpk(s1[rB + 0], s1[rB + 1]);
            lo1 = cvtpk(s1[rB + 2], s1[rB + 3]);
            hi0 = cvtpk(s1[rB + 4], s1[rB + 5]);
            hi1 = cvtpk(s1[rB + 6], s1[rB + 7]);
          }
          const u32 g0 = hib ? lo0 : hi0;
          const u32 g1 = hib ? lo1 : hi1;
          const u32 r0 = (u32)__shfl_xor((int)g0, 32, 64);
          const u32 r1 = (u32)__shfl_xor((int)g1, 32, 64);
          union { u32 u[4]; bf16x8 v; } pu;
          pu.u[0] = hib ? r0 : lo0;
          pu.u[1] = hib ? r1 : lo1;
          pu.u[2] = hib ? hi0 : r0;
          pu.u[3] = hib ? hi1 : r1;
          paf[2 * t + h8] = pu.v;
        }
      }

      // ---- O += P^T @ V (A row = q = crow, B col = d = l31) ----
      __builtin_amdgcn_s_setprio(1);
#pragma unroll
      for (int B = 0; B < 4; B++) {
#pragma unroll
        for (int dt = 0; dt < 4; dt++) {
          const bf16x8 vf = *(const bf16x8*)(
              &Vsc[(32 * dt + l31) * 64 + (((2 * B + hib) ^ (l31 & 7))) * 8]);
          o[dt] = __builtin_amdgcn_mfma_f32_32x32x16_bf16(paf[B], vf, o[dt], 0, 0, 0);
        }
      }
      __builtin_amdgcn_s_setprio(0);
    }

    // single barrier per tile: all waves done reading buf(cur); the barrier's
    // vmcnt(0) drains the prefetch DMA (it had the whole compute phase).
    __syncthreads();
  }

  // epilogue: lane's o[dt][r] is O[q = qw0+crow(r,hib)][d = 32dt+l31];
  // lrow for row crow lives in lane crow (and crow+32) -> bpermute fetch.
#pragma unroll
  for (int r = 0; r < 16; r++) {
    const int cr = (r & 3) + 8 * (r >> 2) + 4 * hib;
    const float linv = 1.0f / __shfl(lrow, cr, 64);
    const size_t rowoff = ((size_t)(b * Lc + qw0 + cr) * Hc + h) * DhC + l31;
#pragma unroll
    for (int dt = 0; dt < 4; dt++)
      O[rowoff + 32 * dt] = f2b(o[dt][r] * linv);
  }
}

// ---------------------------------------------------------------------------
// ws layout (72 MiB + 256 B peak), serial weight-slot reuse:
//   [0,256) flag | WT 8MiB | xc 16MiB | Qb 16MiB | Kb 16MiB | Vb 16MiB
//   Vtb aliases xc (dead after V-gemm); Ob aliases Vb (dead after v-transpose)
// ---------------------------------------------------------------------------
extern "C" void kernel_launch(void* const* d_in, const int* in_sizes, int n_in,
                              void* d_out, int out_size, void* d_ws, size_t ws_size,
                              hipStream_t stream) {
  const void* x  = d_in[0];
  const void* Wq = d_in[1];
  const void* Wk = d_in[2];
  const void* Wv = d_in[3];
  const void* Wo = d_in[4];
  float* out = (float*)d_out;   // reference output dtype: float32 (verified r4)

  char* w = (char*)d_ws;
  const size_t WSZ = (size_t)2048 * 2048;
  const size_t XSZ = (size_t)Bb * Lc * Dc;
  int* flag = (int*)w;
  u16* WT  = (u16*)(w + 256);
  u16* xc  = WT + WSZ;
  u16* Qb  = xc + XSZ;
  u16* Kb  = Qb + XSZ;
  u16* Vb  = Kb + XSZ;
  u16* Vtb = xc;
  u16* Ob  = Vb;

  sniff_dtype<<<1, 256, 0, stream>>>((const u16*)x, flag);
  conv_x<<<(int)(XSZ / 1024), 256, 0, stream>>>(x, xc, flag);

  dim3 tgrid(32, 32);
  dim3 ggrid(32, 16);

  transpose2d_conv<<<tgrid, 256, 0, stream>>>(Wq, WT, flag);
  gemm_bt<<<ggrid, 256, 0, stream>>>(xc, WT, Qb);
  transpose2d_conv<<<tgrid, 256, 0, stream>>>(Wk, WT, flag);
  gemm_bt<<<ggrid, 256, 0, stream>>>(xc, WT, Kb);
  transpose2d_conv<<<tgrid, 256, 0, stream>>>(Wv, WT, flag);
  gemm_bt<<<ggrid, 256, 0, stream>>>(xc, WT, Vb);

  rope_qk<<<(Bb * Lc * Hc * 64) / 256, 256, 0, stream>>>(Qb, Kb);

  dim3 vgrid(2, 32, 32);
  transpose_v_k<<<vgrid, 256, 0, stream>>>(Vb, Vtb);

  dim3 fgrid(16, 32);
  flash_attn<<<fgrid, 256, 0, stream>>>(Qb, Kb, Vtb, Ob);

  transpose2d_conv<<<tgrid, 256, 0, stream>>>(Wo, WT, flag);
  gemm_bt_f32<<<ggrid, 256, 0, stream>>>(Ob, WT, out);
}